// Round 5
// baseline (320.115 us; speedup 1.0000x reference)
//
#include <hip/hip_runtime.h>

#define B_SZ 4
#define SEQ  2048
#define CH   768
#define NH   12
#define HD   64

typedef float f32x4  __attribute__((ext_vector_type(4)));
typedef __bf16 bf16x8 __attribute__((ext_vector_type(8)));
typedef __bf16 bf16x2 __attribute__((ext_vector_type(2)));

#define MFMA16(a,b,c) __builtin_amdgcn_mfma_f32_16x16x32_bf16(a,b,c,0,0,0)

// scale = 1/sqrt(64) * log2(e)  -> softmax uses exp2
#define QSCALE 0.1803368801111204f

#if __has_builtin(__builtin_amdgcn_exp2f)
#define EXP2(x) __builtin_amdgcn_exp2f(x)
#else
#define EXP2(x) exp2f(x)
#endif

// flash LDS swizzle
#define SWZ(row) (((row) ^ ((row) >> 3)) & 7)

__device__ __forceinline__ unsigned pack2(float a, float b) {
    union { bf16x2 v; unsigned u; } p;
    p.v[0] = (__bf16)a; p.v[1] = (__bf16)b;
    return p.u;
}

// async global->LDS, 16B per lane. lds dest must be wave-uniform base + lane*16.
__device__ __forceinline__ void lds_dma16(const void* g, void* l) {
    __builtin_amdgcn_global_load_lds(
        (const __attribute__((address_space(1))) void*)g,
        (__attribute__((address_space(3))) void*)(unsigned)(unsigned long long)l,
        16, 0, 0);
}

// ---------------- fused fp32 -> bf16 convert (x | qkv_w | proj_w in one launch) ------------
#define NBLK_X  6144   // 6291456 / 1024
#define NBLK_W  1728   // 1769472 / 1024
#define NBLK_P   576   //  589824 / 1024
__global__ __launch_bounds__(256) void convert_all(const float* __restrict__ x,
                                                   const float* __restrict__ w,
                                                   const float* __restrict__ p,
                                                   __bf16* __restrict__ ox,
                                                   __bf16* __restrict__ ow,
                                                   __bf16* __restrict__ op) {
    int blk = blockIdx.x;
    const float* src;
    __bf16* dst;
    int base;
    if (blk < NBLK_X)               { src = x; dst = ox; base = blk; }
    else if (blk < NBLK_X + NBLK_W) { src = w; dst = ow; base = blk - NBLK_X; }
    else                            { src = p; dst = op; base = blk - NBLK_X - NBLK_W; }
    int i = (base * 256 + threadIdx.x) * 4;
    float4 v = *(const float4*)(src + i);
    union { __bf16 h[4]; uint2 u; } o;
    o.h[0] = (__bf16)v.x; o.h[1] = (__bf16)v.y; o.h[2] = (__bf16)v.z; o.h[3] = (__bf16)v.w;
    *(uint2*)(dst + i) = o.u;
}

// ---------------- 128x128 tile (BK=64) MFMA mainloop: C = A(MxK) * B(NxK)^T ----------------
// LDS layout: row-major [128][64] bf16, 16B chunk c stored at phys chunk c ^ (row&7).
__device__ __forceinline__ void gemm128_loop(const __bf16* __restrict__ A,
                                             const __bf16* __restrict__ Bm,
                                             int K, int rowBlk, int colBlk,
                                             __bf16* As, __bf16* Bs,
                                             f32x4 acc[4][4]) {
    const int tid  = threadIdx.x;
    const int lane = tid & 63, wid = tid >> 6;
    const int quad = lane >> 4, l16 = lane & 15;
    const int wm = wid >> 1, wn = wid & 1;

    f32x4 z = {0.f, 0.f, 0.f, 0.f};
#pragma unroll
    for (int mi = 0; mi < 4; ++mi)
#pragma unroll
        for (int ni = 0; ni < 4; ++ni) acc[mi][ni] = z;

    for (int k0 = 0; k0 < K; k0 += 64) {
        __syncthreads();
#pragma unroll
        for (int i = 0; i < 4; ++i) {
            int s = i * 256 + tid;
            int row = s >> 3, pc = s & 7;
            int lc = pc ^ (row & 7);
            lds_dma16(A  + (size_t)(rowBlk + row) * K + k0 + lc * 8, As + s * 8);
            lds_dma16(Bm + (size_t)(colBlk + row) * K + k0 + lc * 8, Bs + s * 8);
        }
        __syncthreads();

#pragma unroll
        for (int kc = 0; kc < 2; ++kc) {
            bf16x8 af[4], bfr[4];
#pragma unroll
            for (int mi = 0; mi < 4; ++mi) {
                int row = wm * 64 + mi * 16 + l16;
                int pc = (quad + 4 * kc) ^ (row & 7);
                af[mi] = *(const bf16x8*)(As + row * 64 + pc * 8);
            }
#pragma unroll
            for (int ni = 0; ni < 4; ++ni) {
                int row = wn * 64 + ni * 16 + l16;
                int pc = (quad + 4 * kc) ^ (row & 7);
                bfr[ni] = *(const bf16x8*)(Bs + row * 64 + pc * 8);
            }
#pragma unroll
            for (int mi = 0; mi < 4; ++mi)
#pragma unroll
                for (int ni = 0; ni < 4; ++ni)
                    acc[mi][ni] = MFMA16(af[mi], bfr[ni], acc[mi][ni]);
        }
    }
}

// ---------------- QKV GEMM: X(8192x768) @ Wqkv(2304x768)^T, scatter to Q/K/Vt ----------------
__global__ __launch_bounds__(256) void qkv_gemm(const __bf16* __restrict__ Xb,
                                                const __bf16* __restrict__ Wb,
                                                __bf16* __restrict__ Qb,
                                                __bf16* __restrict__ Kb,
                                                __bf16* __restrict__ Vt) {
    __shared__ __bf16 smem[128 * 128];   // 32 KB: mainloop uses first 16 KB; V-epilogue all
    f32x4 acc[4][4];
    const int rowBlk = blockIdx.x * 128, colBlk = blockIdx.y * 128;
    gemm128_loop(Xb, Wb, CH, rowBlk, colBlk, smem, smem + 128 * 64, acc);

    const int tid = threadIdx.x;
    const int lane = tid & 63, wid = tid >> 6;
    const int quad = lane >> 4, l16 = lane & 15, wm = wid >> 1, wn = wid & 1;
    const int b = rowBlk >> 11, n0 = rowBlk & (SEQ - 1);

    if (colBlk < 2 * CH) {
        const int isK = (colBlk >= CH);
#pragma unroll
        for (int mi = 0; mi < 4; ++mi)
#pragma unroll
            for (int ni = 0; ni < 4; ++ni)
#pragma unroll
                for (int r = 0; r < 4; ++r) {
                    int n = n0 + wm * 64 + mi * 16 + quad * 4 + r;
                    int cc = colBlk - (isK ? CH : 0) + wn * 64 + ni * 16 + l16;
                    int h = cc >> 6, d = cc & 63;
                    size_t idx = (size_t)((b * NH + h) * SEQ + n) * HD + d;
                    float v = acc[mi][ni][r];
                    if (isK) Kb[idx] = (__bf16)v;
                    else     Qb[idx] = (__bf16)(v * QSCALE);
                }
    } else {
        // V: transpose through LDS, write V^T coalesced
        const int vblk = colBlk - 2 * CH;
        __syncthreads();
#pragma unroll
        for (int mi = 0; mi < 4; ++mi)
#pragma unroll
            for (int ni = 0; ni < 4; ++ni)
#pragma unroll
                for (int r = 0; r < 4; ++r) {
                    int rl = wm * 64 + mi * 16 + quad * 4 + r;   // n-local
                    int cl = wn * 64 + ni * 16 + l16;            // d-local
                    smem[cl * 128 + (((rl >> 3) ^ (cl & 15)) << 3) + (rl & 7)] =
                        (__bf16)acc[mi][ni][r];
                }
        __syncthreads();
        const int dl = tid >> 1;
        const int d  = vblk + dl;
        const int h  = d >> 6, dd = d & 63;
        const size_t base = (size_t)((b * NH + h) * HD + dd) * SEQ + n0;
#pragma unroll
        for (int j2 = 0; j2 < 8; ++j2) {
            int j = (tid & 1) * 8 + j2;
            uint4 val = *(const uint4*)(smem + dl * 128 + ((j ^ (dl & 15)) << 3));
            *(uint4*)(Vt + base + j * 8) = val;
        }
    }
}

// ---------------- Flash attention v13 (RESUBMIT — R4 bench was an infra failure) -------------
// v12 wave-split + pinned waves_per_eu. Post-mortem R3: the q_w=64 split was correct but the
// backend allocated for 6 waves/EU (VGPR_Count=84, same as R0) and spilled ~650MB of scratch
// per dispatch, even though grid (768 = 3 blocks/CU) and LDS (51KB -> 3 blocks/CU) make
// >3 waves/EU unreachable. Fix: amdgpu_waves_per_eu(3,3) pins the allocator at 512/3 ~= 168
// regs/lane — enough for the ~160-reg demand (qf 32 + ot 64 + st 32 + transients) — and stops
// the scheduler from chasing occupancy it can never get. Body byte-identical to R3.
__global__ __launch_bounds__(256) __attribute__((amdgpu_waves_per_eu(3, 3)))
void flash_attn(const __bf16* __restrict__ Qb,
                const __bf16* __restrict__ Kb,
                const __bf16* __restrict__ Vt,
                __bf16* __restrict__ Ab) {
    __shared__ __bf16 smem[26112];   // 51 KB: loop = 32KB staging (Ks0|Vs0|Ks1|Vs1);
                                     // epilogue = Sc f32[128][64] (alias 0..16K) | Ob[128][72]
                                     // at 16384 | Lsc 128 f32 at 25600

    const int tid  = threadIdx.x;
    const int lane = tid & 63, wid = tid >> 6;
    const int quad = lane >> 4, l16 = lane & 15;
    const int qh = wid & 1;          // query half  (64 q)
    const int kh = wid >> 1;         // key half    (32 k)

    // XCD-aware decode: blk%8 = XCD; 6 bh x 16 qblk per XCD.
    const int lin  = blockIdx.x;              // 0..767
    const int xcd  = lin & 7, idx = lin >> 3; // idx 0..95
    const int bh   = xcd * 6 + (idx >> 4);    // 0..47
    const int qblk = idx & 15;                // 0..15 (128 queries each)
    const int b    = bh / NH, head = bh - b * NH;

    // Q^T B-frags: 4 groups of 16 queries; lane n=l16=q, k(d) = kcd*32 + quad*8 + j
    bf16x8 qf[4][2];
#pragma unroll
    for (int qg = 0; qg < 4; ++qg) {
        const int q = qblk * 128 + qh * 64 + qg * 16 + l16;
#pragma unroll
        for (int kcd = 0; kcd < 2; ++kcd)
            qf[qg][kcd] = *(const bf16x8*)(Qb + (size_t)(bh * SEQ + q) * HD + kcd * 32 + quad * 8);
    }

    // key permutation (even/odd groups) for zero-cndmask P exchange; this wave's key rows
    const int key_e = ((l16 >> 2) << 3) + (l16 & 3);
    const int key_o = ((((l16 >> 2) ^ 1)) << 3) + 4 + (l16 & 3);
    const int key0 = (kh << 5) + key_e;
    const int key1 = (kh << 5) + key_o;
    const int swz_k0 = SWZ(key0), swz_k1 = SWZ(key1);

    f32x4 ot[4][4];                  // [qgroup][dgroup] partial O^T over this wave's keys
    f32x4 z = {0.f, 0.f, 0.f, 0.f};
#pragma unroll
    for (int qg = 0; qg < 4; ++qg)
#pragma unroll
        for (int dg = 0; dg < 4; ++dg) ot[qg][dg] = z;
    float l[4] = {0.f, 0.f, 0.f, 0.f};

    const __bf16* Kbh = Kb + (size_t)bh * SEQ * HD;
    const __bf16* Vbh = Vt + (size_t)bh * HD * SEQ;

    const int s_row = tid >> 3, s_pc = tid & 7;
    const int s_lc0 = s_pc ^ SWZ(s_row);
    const int s_lc1 = s_pc ^ SWZ(s_row + 32);

// 64-key sub-tile body; wave covers its kh key-half (32 keys) for 64 queries
#define PROCESS(KsP, VsP)                                                                     \
    do {                                                                                      \
        f32x4 st[4][2];                                                                       \
        _Pragma("unroll")                                                                     \
        for (int qg = 0; qg < 4; ++qg) { st[qg][0] = z; st[qg][1] = z; }                      \
        _Pragma("unroll")                                                                     \
        for (int kcd = 0; kcd < 2; ++kcd) {                                                   \
            const int c8 = quad + (kcd << 2);                                                 \
            bf16x8 kf0 = *(const bf16x8*)((KsP) + key0 * 64 + ((c8 ^ swz_k0) << 3));          \
            bf16x8 kf1 = *(const bf16x8*)((KsP) + key1 * 64 + ((c8 ^ swz_k1) << 3));          \
            _Pragma("unroll")                                                                 \
            for (int qg = 0; qg < 4; ++qg) {                                                  \
                st[qg][0] = MFMA16(kf0, qf[qg][kcd], st[qg][0]);                              \
                st[qg][1] = MFMA16(kf1, qf[qg][kcd], st[qg][1]);                              \
            }                                                                                 \
        }                                                                                     \
        bf16x8 pf[4];                                                                         \
        _Pragma("unroll")                                                                     \
        for (int qg = 0; qg < 4; ++qg) {                                                      \
            float p0 = EXP2(st[qg][0][0]), p1 = EXP2(st[qg][0][1]);                           \
            float p2 = EXP2(st[qg][0][2]), p3 = EXP2(st[qg][0][3]);                           \
            float p4 = EXP2(st[qg][1][0]), p5 = EXP2(st[qg][1][1]);                           \
            float p6 = EXP2(st[qg][1][2]), p7 = EXP2(st[qg][1][3]);                           \
            l[qg] += (p0 + p1) + (p2 + p3) + (p4 + p5) + (p6 + p7);                           \
            unsigned w0 = pack2(p0, p1), w1 = pack2(p2, p3);                                  \
            unsigned x0 = pack2(p4, p5), x1 = pack2(p6, p7);                                  \
            unsigned w2 = (unsigned)__shfl_xor((int)x0, 16, 64);                              \
            unsigned w3 = (unsigned)__shfl_xor((int)x1, 16, 64);                              \
            union { bf16x8 v; unsigned u[4]; } f;                                             \
            f.u[0] = w0; f.u[1] = w1; f.u[2] = w2; f.u[3] = w3;                               \
            pf[qg] = f.v;                                                                     \
        }                                                                                     \
        _Pragma("unroll")                                                                     \
        for (int dg = 0; dg < 4; ++dg) {                                                      \
            const int vrow = (dg << 4) + l16;                                                 \
            bf16x8 vf = *(const bf16x8*)((VsP) + vrow * 64 +                                  \
                                         (((quad + (kh << 2)) ^ SWZ(vrow)) << 3));            \
            _Pragma("unroll")                                                                 \
            for (int qg = 0; qg < 4; ++qg)                                                    \
                ot[qg][dg] = MFMA16(vf, pf[qg], ot[qg][dg]);                                  \
        }                                                                                     \
    } while (0)

    for (int kb = 0; kb < SEQ / 128; ++kb) {
        const int kbase = kb * 128;
        __syncthreads();   // prior-iteration LDS readers done
        // sub-tile 0: keys kbase..kbase+63
        lds_dma16(Kbh + (size_t)(kbase + s_row) * HD + s_lc0 * 8,            smem + tid * 8);
        lds_dma16(Kbh + (size_t)(kbase + s_row + 32) * HD + s_lc1 * 8,       smem + 2048 + tid * 8);
        lds_dma16(Vbh + (size_t)s_row * SEQ + kbase + s_lc0 * 8,             smem + 4096 + tid * 8);
        lds_dma16(Vbh + (size_t)(s_row + 32) * SEQ + kbase + s_lc1 * 8,      smem + 6144 + tid * 8);
        // sub-tile 1: keys kbase+64..kbase+127
        lds_dma16(Kbh + (size_t)(kbase + 64 + s_row) * HD + s_lc0 * 8,       smem + 8192 + tid * 8);
        lds_dma16(Kbh + (size_t)(kbase + 96 + s_row) * HD + s_lc1 * 8,       smem + 10240 + tid * 8);
        lds_dma16(Vbh + (size_t)s_row * SEQ + kbase + 64 + s_lc0 * 8,        smem + 12288 + tid * 8);
        lds_dma16(Vbh + (size_t)(s_row + 32) * SEQ + kbase + 64 + s_lc1 * 8, smem + 14336 + tid * 8);
        __syncthreads();   // drains dma

        PROCESS(smem, smem + 4096);
        PROCESS(smem + 8192, smem + 12288);
    }
#undef PROCESS

    // quad-reduce l: each lane then holds the 32-key partial sum for query qg*16+l16
#pragma unroll
    for (int qg = 0; qg < 4; ++qg) {
        l[qg] += __shfl_xor(l[qg], 16, 64);
        l[qg] += __shfl_xor(l[qg], 32, 64);
    }

    // ---- cross-wave (key-half) reduction + normalize + coalesced store ----
    __syncthreads();                                  // loop readers done; staging area dead
    float* Sc  = (float*)smem;                        // [128][64] f32 partials (32 KB)
    float* Lsc = (float*)(smem + 25600);              // 128 f32 partial denominators
    __bf16 (*Ob)[72] = (__bf16(*)[72])(smem + 16384); // transpose buffer (18 KB)

    if (kh == 1) {
#pragma unroll
        for (int qg = 0; qg < 4; ++qg) {
            const int qrow = (qh << 6) + (qg << 4) + l16;
#pragma unroll
            for (int dg = 0; dg < 4; ++dg)
                *(f32x4*)(Sc + qrow * 64 + (dg << 4) + (quad << 2)) = ot[qg][dg];
            if (quad == 0) Lsc[qrow] = l[qg];
        }
    }
    __syncthreads();
    if (kh == 0) {
#pragma unroll
        for (int qg = 0; qg < 4; ++qg) {
            const int qrow = (qh << 6) + (qg << 4) + l16;
            const float r = 1.f / (l[qg] + Lsc[qrow]);
#pragma unroll
            for (int dg = 0; dg < 4; ++dg) {
                f32x4 o = ot[qg][dg] + *(const f32x4*)(Sc + qrow * 64 + (dg << 4) + (quad << 2));
#pragma unroll
                for (int rr = 0; rr < 4; ++rr)
                    Ob[qrow][(dg << 4) + (quad << 2) + rr] = (__bf16)(o[rr] * r);
            }
        }
    }
    __syncthreads();
    {
        const int row = tid >> 1, c0 = (tid & 1) * 32;
        __bf16* dst = Ab + (size_t)(b * SEQ + qblk * 128 + row) * CH + head * HD + c0;
#pragma unroll
        for (int j = 0; j < 4; ++j)
            *(uint4*)(dst + j * 8) = *(const uint4*)(&Ob[row][c0 + j * 8]);
    }
}

// ---------------- Projection GEMM: Attn(8192x768) @ proj_w(768x768)^T + bias ----------------
__global__ __launch_bounds__(256) void proj_gemm(const __bf16* __restrict__ Ab,
                                                 const __bf16* __restrict__ Pw,
                                                 const float* __restrict__ bias,
                                                 float* __restrict__ out) {
    __shared__ __bf16 As[128 * 64];
    __shared__ __bf16 Bs[128 * 64];
    f32x4 acc[4][4];
    const int rowBlk = blockIdx.x * 128, colBlk = blockIdx.y * 128;
    gemm128_loop(Ab, Pw, CH, rowBlk, colBlk, As, Bs, acc);

    const int lane = threadIdx.x & 63, wid = threadIdx.x >> 6;
    const int quad = lane >> 4, l16 = lane & 15, wm = wid >> 1, wn = wid & 1;
#pragma unroll
    for (int mi = 0; mi < 4; ++mi)
#pragma unroll
        for (int ni = 0; ni < 4; ++ni)
#pragma unroll
            for (int r = 0; r < 4; ++r) {
                int row = rowBlk + wm * 64 + mi * 16 + quad * 4 + r;
                int col = colBlk + wn * 64 + ni * 16 + l16;
                out[(size_t)row * CH + col] = acc[mi][ni][r] + bias[col];
            }
}

extern "C" void kernel_launch(void* const* d_in, const int* in_sizes, int n_in,
                              void* d_out, int out_size, void* d_ws, size_t ws_size,
                              hipStream_t stream) {
    const float* x      = (const float*)d_in[0];
    const float* qkv_w  = (const float*)d_in[1];
    const float* proj_w = (const float*)d_in[2];
    const float* proj_b = (const float*)d_in[3];
    float* out = (float*)d_out;

    char* ws = (char*)d_ws;
    const size_t nX = (size_t)B_SZ * SEQ * CH;
    const size_t nW = (size_t)3 * CH * CH;
    const size_t nP = (size_t)CH * CH;
    const size_t nQ = (size_t)B_SZ * NH * SEQ * HD;

    __bf16* Xb = (__bf16*)(ws);
    __bf16* Wb = (__bf16*)(ws + 2 * nX);
    __bf16* Pw = (__bf16*)(ws + 2 * (nX + nW));
    __bf16* Qb = (__bf16*)(ws + 2 * (nX + nW + nP));
    __bf16* Kb = (__bf16*)(ws + 2 * (nX + nW + nP + nQ));
    __bf16* Vt = (__bf16*)(ws + 2 * (nX + nW + nP + 2 * nQ));
    __bf16* Ab = (__bf16*)(ws + 2 * (nX + nW + nP + 3 * nQ));

    convert_all<<<NBLK_X + NBLK_W + NBLK_P, 256, 0, stream>>>(x, qkv_w, proj_w, Xb, Wb, Pw);

    qkv_gemm<<<dim3((B_SZ * SEQ) / 128, (3 * CH) / 128), 256, 0, stream>>>(Xb, Wb, Qb, Kb, Vt);

    flash_attn<<<768, 256, 0, stream>>>(Qb, Kb, Vt, Ab);

    proj_gemm<<<dim3((B_SZ * SEQ) / 128, CH / 128), 256, 0, stream>>>(Ab, Pw, proj_b, out);
}

// Round 6
// 222.254 us; speedup vs baseline: 1.4403x; 1.4403x over previous
//
#include <hip/hip_runtime.h>

#define B_SZ 4
#define SEQ  2048
#define CH   768
#define NH   12
#define HD   64

typedef float f32x4  __attribute__((ext_vector_type(4)));
typedef __bf16 bf16x8 __attribute__((ext_vector_type(8)));
typedef __bf16 bf16x2 __attribute__((ext_vector_type(2)));

#define MFMA16(a,b,c) __builtin_amdgcn_mfma_f32_16x16x32_bf16(a,b,c,0,0,0)

// scale = 1/sqrt(64) * log2(e)  -> softmax uses exp2
#define QSCALE 0.1803368801111204f

#if __has_builtin(__builtin_amdgcn_exp2f)
#define EXP2(x) __builtin_amdgcn_exp2f(x)
#else
#define EXP2(x) exp2f(x)
#endif

// flash LDS swizzle
#define SWZ(row) (((row) ^ ((row) >> 3)) & 7)

__device__ __forceinline__ unsigned pack2(float a, float b) {
    union { bf16x2 v; unsigned u; } p;
    p.v[0] = (__bf16)a; p.v[1] = (__bf16)b;
    return p.u;
}

// async global->LDS, 16B per lane. lds dest must be wave-uniform base + lane*16.
__device__ __forceinline__ void lds_dma16(const void* g, void* l) {
    __builtin_amdgcn_global_load_lds(
        (const __attribute__((address_space(1))) void*)g,
        (__attribute__((address_space(3))) void*)(unsigned)(unsigned long long)l,
        16, 0, 0);
}

// ---------------- fused fp32 -> bf16 convert (x | qkv_w | proj_w in one launch) ------------
#define NBLK_X  6144   // 6291456 / 1024
#define NBLK_W  1728   // 1769472 / 1024
#define NBLK_P   576   //  589824 / 1024
__global__ __launch_bounds__(256) void convert_all(const float* __restrict__ x,
                                                   const float* __restrict__ w,
                                                   const float* __restrict__ p,
                                                   __bf16* __restrict__ ox,
                                                   __bf16* __restrict__ ow,
                                                   __bf16* __restrict__ op) {
    int blk = blockIdx.x;
    const float* src;
    __bf16* dst;
    int base;
    if (blk < NBLK_X)               { src = x; dst = ox; base = blk; }
    else if (blk < NBLK_X + NBLK_W) { src = w; dst = ow; base = blk - NBLK_X; }
    else                            { src = p; dst = op; base = blk - NBLK_X - NBLK_W; }
    int i = (base * 256 + threadIdx.x) * 4;
    float4 v = *(const float4*)(src + i);
    union { __bf16 h[4]; uint2 u; } o;
    o.h[0] = (__bf16)v.x; o.h[1] = (__bf16)v.y; o.h[2] = (__bf16)v.z; o.h[3] = (__bf16)v.w;
    *(uint2*)(dst + i) = o.u;
}

// ---------------- 128x128 tile (BK=64) MFMA mainloop: C = A(MxK) * B(NxK)^T ----------------
// LDS layout: row-major [128][64] bf16, 16B chunk c stored at phys chunk c ^ (row&7).
__device__ __forceinline__ void gemm128_loop(const __bf16* __restrict__ A,
                                             const __bf16* __restrict__ Bm,
                                             int K, int rowBlk, int colBlk,
                                             __bf16* As, __bf16* Bs,
                                             f32x4 acc[4][4]) {
    const int tid  = threadIdx.x;
    const int lane = tid & 63, wid = tid >> 6;
    const int quad = lane >> 4, l16 = lane & 15;
    const int wm = wid >> 1, wn = wid & 1;

    f32x4 z = {0.f, 0.f, 0.f, 0.f};
#pragma unroll
    for (int mi = 0; mi < 4; ++mi)
#pragma unroll
        for (int ni = 0; ni < 4; ++ni) acc[mi][ni] = z;

    for (int k0 = 0; k0 < K; k0 += 64) {
        __syncthreads();
#pragma unroll
        for (int i = 0; i < 4; ++i) {
            int s = i * 256 + tid;
            int row = s >> 3, pc = s & 7;
            int lc = pc ^ (row & 7);
            lds_dma16(A  + (size_t)(rowBlk + row) * K + k0 + lc * 8, As + s * 8);
            lds_dma16(Bm + (size_t)(colBlk + row) * K + k0 + lc * 8, Bs + s * 8);
        }
        __syncthreads();

#pragma unroll
        for (int kc = 0; kc < 2; ++kc) {
            bf16x8 af[4], bfr[4];
#pragma unroll
            for (int mi = 0; mi < 4; ++mi) {
                int row = wm * 64 + mi * 16 + l16;
                int pc = (quad + 4 * kc) ^ (row & 7);
                af[mi] = *(const bf16x8*)(As + row * 64 + pc * 8);
            }
#pragma unroll
            for (int ni = 0; ni < 4; ++ni) {
                int row = wn * 64 + ni * 16 + l16;
                int pc = (quad + 4 * kc) ^ (row & 7);
                bfr[ni] = *(const bf16x8*)(Bs + row * 64 + pc * 8);
            }
#pragma unroll
            for (int mi = 0; mi < 4; ++mi)
#pragma unroll
                for (int ni = 0; ni < 4; ++ni)
                    acc[mi][ni] = MFMA16(af[mi], bfr[ni], acc[mi][ni]);
        }
    }
}

// ---------------- QKV GEMM: X(8192x768) @ Wqkv(2304x768)^T, scatter to Q/K/Vt ----------------
__global__ __launch_bounds__(256) void qkv_gemm(const __bf16* __restrict__ Xb,
                                                const __bf16* __restrict__ Wb,
                                                __bf16* __restrict__ Qb,
                                                __bf16* __restrict__ Kb,
                                                __bf16* __restrict__ Vt) {
    __shared__ __bf16 smem[128 * 128];   // 32 KB: mainloop uses first 16 KB; V-epilogue all
    f32x4 acc[4][4];
    const int rowBlk = blockIdx.x * 128, colBlk = blockIdx.y * 128;
    gemm128_loop(Xb, Wb, CH, rowBlk, colBlk, smem, smem + 128 * 64, acc);

    const int tid = threadIdx.x;
    const int lane = tid & 63, wid = tid >> 6;
    const int quad = lane >> 4, l16 = lane & 15, wm = wid >> 1, wn = wid & 1;
    const int b = rowBlk >> 11, n0 = rowBlk & (SEQ - 1);

    if (colBlk < 2 * CH) {
        const int isK = (colBlk >= CH);
#pragma unroll
        for (int mi = 0; mi < 4; ++mi)
#pragma unroll
            for (int ni = 0; ni < 4; ++ni)
#pragma unroll
                for (int r = 0; r < 4; ++r) {
                    int n = n0 + wm * 64 + mi * 16 + quad * 4 + r;
                    int cc = colBlk - (isK ? CH : 0) + wn * 64 + ni * 16 + l16;
                    int h = cc >> 6, d = cc & 63;
                    size_t idx = (size_t)((b * NH + h) * SEQ + n) * HD + d;
                    float v = acc[mi][ni][r];
                    if (isK) Kb[idx] = (__bf16)v;
                    else     Qb[idx] = (__bf16)(v * QSCALE);
                }
    } else {
        // V: transpose through LDS, write V^T coalesced
        const int vblk = colBlk - 2 * CH;
        __syncthreads();
#pragma unroll
        for (int mi = 0; mi < 4; ++mi)
#pragma unroll
            for (int ni = 0; ni < 4; ++ni)
#pragma unroll
                for (int r = 0; r < 4; ++r) {
                    int rl = wm * 64 + mi * 16 + quad * 4 + r;   // n-local
                    int cl = wn * 64 + ni * 16 + l16;            // d-local
                    smem[cl * 128 + (((rl >> 3) ^ (cl & 15)) << 3) + (rl & 7)] =
                        (__bf16)acc[mi][ni][r];
                }
        __syncthreads();
        const int dl = tid >> 1;
        const int d  = vblk + dl;
        const int h  = d >> 6, dd = d & 63;
        const size_t base = (size_t)((b * NH + h) * HD + dd) * SEQ + n0;
#pragma unroll
        for (int j2 = 0; j2 < 8; ++j2) {
            int j = (tid & 1) * 8 + j2;
            uint4 val = *(const uint4*)(smem + dl * 128 + ((j ^ (dl & 15)) << 3));
            *(uint4*)(Vt + base + j * 8) = val;
        }
    }
}

// ---------------- Flash attention v14: wave-split + per-qg interleaved softmax ---------------
// Post-mortem R5: both occupancy hints (launch_bounds(256,3), waves_per_eu(3,3)) left the v12
// structure spilling ~650MB/dispatch — the peak live set (qf32 + ot64 + st32 + pf16 + temps
// ~ 170-190) exceeds the 3-wave/EU budget. Fix the DEMAND: hoist the 4 K-frags (16 regs,
// shared by all qg) and process one query-group at a time (QK -> exp/pack -> pf[qg]), so only
// one st0/st1 pair (8 regs) is live at once. Peak ~ 145 regs. launch_bounds(256,2) gives the
// allocator a 256-reg ceiling (cannot be forced to spill); demand ~145 should still yield
// 3 blocks/CU (LDS-limited). Decomposition/staging/epilogue identical to v12 (passed).
__global__ __launch_bounds__(256, 2)
void flash_attn(const __bf16* __restrict__ Qb,
                const __bf16* __restrict__ Kb,
                const __bf16* __restrict__ Vt,
                __bf16* __restrict__ Ab) {
    __shared__ __bf16 smem[26112];   // 51 KB: loop = 32KB staging (Ks0|Vs0|Ks1|Vs1);
                                     // epilogue = Sc f32[128][64] (alias 0..16K) | Ob[128][72]
                                     // at 16384 | Lsc 128 f32 at 25600

    const int tid  = threadIdx.x;
    const int lane = tid & 63, wid = tid >> 6;
    const int quad = lane >> 4, l16 = lane & 15;
    const int qh = wid & 1;          // query half  (64 q)
    const int kh = wid >> 1;         // key half    (32 k)

    // XCD-aware decode: blk%8 = XCD; 6 bh x 16 qblk per XCD.
    const int lin  = blockIdx.x;              // 0..767
    const int xcd  = lin & 7, idx = lin >> 3; // idx 0..95
    const int bh   = xcd * 6 + (idx >> 4);    // 0..47
    const int qblk = idx & 15;                // 0..15 (128 queries each)
    const int b    = bh / NH, head = bh - b * NH;

    // Q^T B-frags: 4 groups of 16 queries; lane n=l16=q, k(d) = kcd*32 + quad*8 + j
    bf16x8 qf[4][2];
#pragma unroll
    for (int qg = 0; qg < 4; ++qg) {
        const int q = qblk * 128 + qh * 64 + qg * 16 + l16;
#pragma unroll
        for (int kcd = 0; kcd < 2; ++kcd)
            qf[qg][kcd] = *(const bf16x8*)(Qb + (size_t)(bh * SEQ + q) * HD + kcd * 32 + quad * 8);
    }

    // key permutation (even/odd groups) for zero-cndmask P exchange; this wave's key rows
    const int key_e = ((l16 >> 2) << 3) + (l16 & 3);
    const int key_o = ((((l16 >> 2) ^ 1)) << 3) + 4 + (l16 & 3);
    const int key0 = (kh << 5) + key_e;
    const int key1 = (kh << 5) + key_o;
    const int swz_k0 = SWZ(key0), swz_k1 = SWZ(key1);

    f32x4 ot[4][4];                  // [qgroup][dgroup] partial O^T over this wave's keys
    f32x4 z = {0.f, 0.f, 0.f, 0.f};
#pragma unroll
    for (int qg = 0; qg < 4; ++qg)
#pragma unroll
        for (int dg = 0; dg < 4; ++dg) ot[qg][dg] = z;
    float l[4] = {0.f, 0.f, 0.f, 0.f};

    const __bf16* Kbh = Kb + (size_t)bh * SEQ * HD;
    const __bf16* Vbh = Vt + (size_t)bh * HD * SEQ;

    const int s_row = tid >> 3, s_pc = tid & 7;
    const int s_lc0 = s_pc ^ SWZ(s_row);
    const int s_lc1 = s_pc ^ SWZ(s_row + 32);

// 64-key sub-tile body; wave covers its kh key-half (32 keys) for 64 queries.
// K frags hoisted (shared by all qg); per-qg QK -> exp/pack keeps only st0/st1 (8 regs) live.
#define PROCESS(KsP, VsP)                                                                     \
    do {                                                                                      \
        bf16x8 kf[2][2];                                                                      \
        _Pragma("unroll")                                                                     \
        for (int kcd = 0; kcd < 2; ++kcd) {                                                   \
            const int c8 = quad + (kcd << 2);                                                 \
            kf[kcd][0] = *(const bf16x8*)((KsP) + key0 * 64 + ((c8 ^ swz_k0) << 3));          \
            kf[kcd][1] = *(const bf16x8*)((KsP) + key1 * 64 + ((c8 ^ swz_k1) << 3));          \
        }                                                                                     \
        bf16x8 pf[4];                                                                         \
        _Pragma("unroll")                                                                     \
        for (int qg = 0; qg < 4; ++qg) {                                                      \
            f32x4 st0 = z, st1 = z;                                                           \
            _Pragma("unroll")                                                                 \
            for (int kcd = 0; kcd < 2; ++kcd) {                                               \
                st0 = MFMA16(kf[kcd][0], qf[qg][kcd], st0);                                   \
                st1 = MFMA16(kf[kcd][1], qf[qg][kcd], st1);                                   \
            }                                                                                 \
            float p0 = EXP2(st0[0]), p1 = EXP2(st0[1]);                                       \
            float p2 = EXP2(st0[2]), p3 = EXP2(st0[3]);                                       \
            float p4 = EXP2(st1[0]), p5 = EXP2(st1[1]);                                       \
            float p6 = EXP2(st1[2]), p7 = EXP2(st1[3]);                                       \
            l[qg] += (p0 + p1) + (p2 + p3) + (p4 + p5) + (p6 + p7);                           \
            unsigned w0 = pack2(p0, p1), w1 = pack2(p2, p3);                                  \
            unsigned x0 = pack2(p4, p5), x1 = pack2(p6, p7);                                  \
            unsigned w2 = (unsigned)__shfl_xor((int)x0, 16, 64);                              \
            unsigned w3 = (unsigned)__shfl_xor((int)x1, 16, 64);                              \
            union { bf16x8 v; unsigned u[4]; } f;                                             \
            f.u[0] = w0; f.u[1] = w1; f.u[2] = w2; f.u[3] = w3;                               \
            pf[qg] = f.v;                                                                     \
        }                                                                                     \
        _Pragma("unroll")                                                                     \
        for (int dg = 0; dg < 4; ++dg) {                                                      \
            const int vrow = (dg << 4) + l16;                                                 \
            bf16x8 vf = *(const bf16x8*)((VsP) + vrow * 64 +                                  \
                                         (((quad + (kh << 2)) ^ SWZ(vrow)) << 3));            \
            _Pragma("unroll")                                                                 \
            for (int qg = 0; qg < 4; ++qg)                                                    \
                ot[qg][dg] = MFMA16(vf, pf[qg], ot[qg][dg]);                                  \
        }                                                                                     \
    } while (0)

    for (int kb = 0; kb < SEQ / 128; ++kb) {
        const int kbase = kb * 128;
        __syncthreads();   // prior-iteration LDS readers done
        // sub-tile 0: keys kbase..kbase+63
        lds_dma16(Kbh + (size_t)(kbase + s_row) * HD + s_lc0 * 8,            smem + tid * 8);
        lds_dma16(Kbh + (size_t)(kbase + s_row + 32) * HD + s_lc1 * 8,       smem + 2048 + tid * 8);
        lds_dma16(Vbh + (size_t)s_row * SEQ + kbase + s_lc0 * 8,             smem + 4096 + tid * 8);
        lds_dma16(Vbh + (size_t)(s_row + 32) * SEQ + kbase + s_lc1 * 8,      smem + 6144 + tid * 8);
        // sub-tile 1: keys kbase+64..kbase+127
        lds_dma16(Kbh + (size_t)(kbase + 64 + s_row) * HD + s_lc0 * 8,       smem + 8192 + tid * 8);
        lds_dma16(Kbh + (size_t)(kbase + 96 + s_row) * HD + s_lc1 * 8,       smem + 10240 + tid * 8);
        lds_dma16(Vbh + (size_t)s_row * SEQ + kbase + 64 + s_lc0 * 8,        smem + 12288 + tid * 8);
        lds_dma16(Vbh + (size_t)(s_row + 32) * SEQ + kbase + 64 + s_lc1 * 8, smem + 14336 + tid * 8);
        __syncthreads();   // drains dma

        PROCESS(smem, smem + 4096);
        PROCESS(smem + 8192, smem + 12288);
    }
#undef PROCESS

    // quad-reduce l: each lane then holds the 32-key partial sum for query qg*16+l16
#pragma unroll
    for (int qg = 0; qg < 4; ++qg) {
        l[qg] += __shfl_xor(l[qg], 16, 64);
        l[qg] += __shfl_xor(l[qg], 32, 64);
    }

    // ---- cross-wave (key-half) reduction + normalize + coalesced store ----
    __syncthreads();                                  // loop readers done; staging area dead
    float* Sc  = (float*)smem;                        // [128][64] f32 partials (32 KB)
    float* Lsc = (float*)(smem + 25600);              // 128 f32 partial denominators
    __bf16 (*Ob)[72] = (__bf16(*)[72])(smem + 16384); // transpose buffer (18 KB)

    if (kh == 1) {
#pragma unroll
        for (int qg = 0; qg < 4; ++qg) {
            const int qrow = (qh << 6) + (qg << 4) + l16;
#pragma unroll
            for (int dg = 0; dg < 4; ++dg)
                *(f32x4*)(Sc + qrow * 64 + (dg << 4) + (quad << 2)) = ot[qg][dg];
            if (quad == 0) Lsc[qrow] = l[qg];
        }
    }
    __syncthreads();
    if (kh == 0) {
#pragma unroll
        for (int qg = 0; qg < 4; ++qg) {
            const int qrow = (qh << 6) + (qg << 4) + l16;
            const float r = 1.f / (l[qg] + Lsc[qrow]);
#pragma unroll
            for (int dg = 0; dg < 4; ++dg) {
                f32x4 o = ot[qg][dg] + *(const f32x4*)(Sc + qrow * 64 + (dg << 4) + (quad << 2));
#pragma unroll
                for (int rr = 0; rr < 4; ++rr)
                    Ob[qrow][(dg << 4) + (quad << 2) + rr] = (__bf16)(o[rr] * r);
            }
        }
    }
    __syncthreads();
    {
        const int row = tid >> 1, c0 = (tid & 1) * 32;
        __bf16* dst = Ab + (size_t)(b * SEQ + qblk * 128 + row) * CH + head * HD + c0;
#pragma unroll
        for (int j = 0; j < 4; ++j)
            *(uint4*)(dst + j * 8) = *(const uint4*)(&Ob[row][c0 + j * 8]);
    }
}

// ---------------- Projection GEMM: Attn(8192x768) @ proj_w(768x768)^T + bias ----------------
__global__ __launch_bounds__(256) void proj_gemm(const __bf16* __restrict__ Ab,
                                                 const __bf16* __restrict__ Pw,
                                                 const float* __restrict__ bias,
                                                 float* __restrict__ out) {
    __shared__ __bf16 As[128 * 64];
    __shared__ __bf16 Bs[128 * 64];
    f32x4 acc[4][4];
    const int rowBlk = blockIdx.x * 128, colBlk = blockIdx.y * 128;
    gemm128_loop(Ab, Pw, CH, rowBlk, colBlk, As, Bs, acc);

    const int lane = threadIdx.x & 63, wid = threadIdx.x >> 6;
    const int quad = lane >> 4, l16 = lane & 15, wm = wid >> 1, wn = wid & 1;
#pragma unroll
    for (int mi = 0; mi < 4; ++mi)
#pragma unroll
        for (int ni = 0; ni < 4; ++ni)
#pragma unroll
            for (int r = 0; r < 4; ++r) {
                int row = rowBlk + wm * 64 + mi * 16 + quad * 4 + r;
                int col = colBlk + wn * 64 + ni * 16 + l16;
                out[(size_t)row * CH + col] = acc[mi][ni][r] + bias[col];
            }
}

extern "C" void kernel_launch(void* const* d_in, const int* in_sizes, int n_in,
                              void* d_out, int out_size, void* d_ws, size_t ws_size,
                              hipStream_t stream) {
    const float* x      = (const float*)d_in[0];
    const float* qkv_w  = (const float*)d_in[1];
    const float* proj_w = (const float*)d_in[2];
    const float* proj_b = (const float*)d_in[3];
    float* out = (float*)d_out;

    char* ws = (char*)d_ws;
    const size_t nX = (size_t)B_SZ * SEQ * CH;
    const size_t nW = (size_t)3 * CH * CH;
    const size_t nP = (size_t)CH * CH;
    const size_t nQ = (size_t)B_SZ * NH * SEQ * HD;

    __bf16* Xb = (__bf16*)(ws);
    __bf16* Wb = (__bf16*)(ws + 2 * nX);
    __bf16* Pw = (__bf16*)(ws + 2 * (nX + nW));
    __bf16* Qb = (__bf16*)(ws + 2 * (nX + nW + nP));
    __bf16* Kb = (__bf16*)(ws + 2 * (nX + nW + nP + nQ));
    __bf16* Vt = (__bf16*)(ws + 2 * (nX + nW + nP + 2 * nQ));
    __bf16* Ab = (__bf16*)(ws + 2 * (nX + nW + nP + 3 * nQ));

    convert_all<<<NBLK_X + NBLK_W + NBLK_P, 256, 0, stream>>>(x, qkv_w, proj_w, Xb, Wb, Pw);

    qkv_gemm<<<dim3((B_SZ * SEQ) / 128, (3 * CH) / 128), 256, 0, stream>>>(Xb, Wb, Qb, Kb, Vt);

    flash_attn<<<768, 256, 0, stream>>>(Qb, Kb, Vt, Ab);

    proj_gemm<<<dim3((B_SZ * SEQ) / 128, CH / 128), 256, 0, stream>>>(Ab, Pw, proj_b, out);
}

// Round 7
// 209.748 us; speedup vs baseline: 1.5262x; 1.0596x over previous
//
#include <hip/hip_runtime.h>

#define B_SZ 4
#define SEQ  2048
#define CH   768
#define NH   12
#define HD   64

typedef float f32x4  __attribute__((ext_vector_type(4)));
typedef __bf16 bf16x8 __attribute__((ext_vector_type(8)));
typedef __bf16 bf16x2 __attribute__((ext_vector_type(2)));

#define MFMA16(a,b,c) __builtin_amdgcn_mfma_f32_16x16x32_bf16(a,b,c,0,0,0)

// scale = 1/sqrt(64) * log2(e)  -> softmax uses exp2
#define QSCALE 0.1803368801111204f

#if __has_builtin(__builtin_amdgcn_exp2f)
#define EXP2(x) __builtin_amdgcn_exp2f(x)
#else
#define EXP2(x) exp2f(x)
#endif

// flash LDS swizzle (kept from R8; conflict counter proved layout-insensitive, not a lever)
#define SWZ(row) (((row) ^ ((row) >> 3)) & 7)

__device__ __forceinline__ unsigned pack2(float a, float b) {
    union { bf16x2 v; unsigned u; } p;
    p.v[0] = (__bf16)a; p.v[1] = (__bf16)b;
    return p.u;
}

// async global->LDS, 16B per lane. lds dest must be wave-uniform base + lane*16.
__device__ __forceinline__ void lds_dma16(const void* g, void* l) {
    __builtin_amdgcn_global_load_lds(
        (const __attribute__((address_space(1))) void*)g,
        (__attribute__((address_space(3))) void*)(unsigned)(unsigned long long)l,
        16, 0, 0);
}

// ---------------- fused fp32 -> bf16 convert (x | qkv_w | proj_w in one launch) ------------
#define NBLK_X  6144   // 6291456 / 1024
#define NBLK_W  1728   // 1769472 / 1024
#define NBLK_P   576   //  589824 / 1024
__global__ __launch_bounds__(256) void convert_all(const float* __restrict__ x,
                                                   const float* __restrict__ w,
                                                   const float* __restrict__ p,
                                                   __bf16* __restrict__ ox,
                                                   __bf16* __restrict__ ow,
                                                   __bf16* __restrict__ op) {
    int blk = blockIdx.x;
    const float* src;
    __bf16* dst;
    int base;
    if (blk < NBLK_X)               { src = x; dst = ox; base = blk; }
    else if (blk < NBLK_X + NBLK_W) { src = w; dst = ow; base = blk - NBLK_X; }
    else                            { src = p; dst = op; base = blk - NBLK_X - NBLK_W; }
    int i = (base * 256 + threadIdx.x) * 4;
    float4 v = *(const float4*)(src + i);
    union { __bf16 h[4]; uint2 u; } o;
    o.h[0] = (__bf16)v.x; o.h[1] = (__bf16)v.y; o.h[2] = (__bf16)v.z; o.h[3] = (__bf16)v.w;
    *(uint2*)(dst + i) = o.u;
}

// ---------------- 128x128 tile (BK=64) MFMA mainloop: C = A(MxK) * B(NxK)^T ----------------
// LDS layout: row-major [128][64] bf16, 16B chunk c stored at phys chunk c ^ (row&7).
__device__ __forceinline__ void gemm128_loop(const __bf16* __restrict__ A,
                                             const __bf16* __restrict__ Bm,
                                             int K, int rowBlk, int colBlk,
                                             __bf16* As, __bf16* Bs,
                                             f32x4 acc[4][4]) {
    const int tid  = threadIdx.x;
    const int lane = tid & 63, wid = tid >> 6;
    const int quad = lane >> 4, l16 = lane & 15;
    const int wm = wid >> 1, wn = wid & 1;

    f32x4 z = {0.f, 0.f, 0.f, 0.f};
#pragma unroll
    for (int mi = 0; mi < 4; ++mi)
#pragma unroll
        for (int ni = 0; ni < 4; ++ni) acc[mi][ni] = z;

    for (int k0 = 0; k0 < K; k0 += 64) {
        __syncthreads();
#pragma unroll
        for (int i = 0; i < 4; ++i) {
            int s = i * 256 + tid;
            int row = s >> 3, pc = s & 7;
            int lc = pc ^ (row & 7);
            lds_dma16(A  + (size_t)(rowBlk + row) * K + k0 + lc * 8, As + s * 8);
            lds_dma16(Bm + (size_t)(colBlk + row) * K + k0 + lc * 8, Bs + s * 8);
        }
        __syncthreads();

#pragma unroll
        for (int kc = 0; kc < 2; ++kc) {
            bf16x8 af[4], bfr[4];
#pragma unroll
            for (int mi = 0; mi < 4; ++mi) {
                int row = wm * 64 + mi * 16 + l16;
                int pc = (quad + 4 * kc) ^ (row & 7);
                af[mi] = *(const bf16x8*)(As + row * 64 + pc * 8);
            }
#pragma unroll
            for (int ni = 0; ni < 4; ++ni) {
                int row = wn * 64 + ni * 16 + l16;
                int pc = (quad + 4 * kc) ^ (row & 7);
                bfr[ni] = *(const bf16x8*)(Bs + row * 64 + pc * 8);
            }
#pragma unroll
            for (int mi = 0; mi < 4; ++mi)
#pragma unroll
                for (int ni = 0; ni < 4; ++ni)
                    acc[mi][ni] = MFMA16(af[mi], bfr[ni], acc[mi][ni]);
        }
    }
}

// ---------------- QKV GEMM: X(8192x768) @ Wqkv(2304x768)^T, scatter to Q/K/Vt ----------------
// R7: Q/K epilogue vectorized via LDS transpose (was 64 scalar bf16 stores/thread at 32B
// coalescing). Stage acc into [128][128] bf16 with col' = cl ^ ((rl&15)<<3) (8-granular XOR,
// ~2-way write conflicts = free), then each thread stores 8x uint4, 128B-coalesced per head.
__global__ __launch_bounds__(256) void qkv_gemm(const __bf16* __restrict__ Xb,
                                                const __bf16* __restrict__ Wb,
                                                __bf16* __restrict__ Qb,
                                                __bf16* __restrict__ Kb,
                                                __bf16* __restrict__ Vt) {
    __shared__ __bf16 smem[128 * 128];   // 32 KB: mainloop uses first 16 KB; epilogue all
    f32x4 acc[4][4];
    const int rowBlk = blockIdx.x * 128, colBlk = blockIdx.y * 128;
    gemm128_loop(Xb, Wb, CH, rowBlk, colBlk, smem, smem + 128 * 64, acc);

    const int tid = threadIdx.x;
    const int lane = tid & 63, wid = tid >> 6;
    const int quad = lane >> 4, l16 = lane & 15, wm = wid >> 1, wn = wid & 1;
    const int b = rowBlk >> 11, n0 = rowBlk & (SEQ - 1);

    if (colBlk < 2 * CH) {
        const int isK = (colBlk >= CH);
        const float sc = isK ? 1.f : QSCALE;
        const int hb = (colBlk - (isK ? CH : 0)) >> 6;   // base head of this 128-col block
        __syncthreads();   // mainloop LDS readers done; reuse as [128][128]
#pragma unroll
        for (int mi = 0; mi < 4; ++mi)
#pragma unroll
            for (int ni = 0; ni < 4; ++ni)
#pragma unroll
                for (int r = 0; r < 4; ++r) {
                    int rl = wm * 64 + mi * 16 + quad * 4 + r;   // n-local
                    int cl = wn * 64 + ni * 16 + l16;            // col-local (2 heads x 64 d)
                    smem[rl * 128 + (cl ^ ((rl & 15) << 3))] = (__bf16)(acc[mi][ni][r] * sc);
                }
        __syncthreads();
        __bf16* dst0 = isK ? Kb : Qb;
        const int rbase = tid >> 4;          // 0..15
        const int c = (tid & 15) * 8;        // 0..120, 8-aligned
        const int h = hb + (c >> 6), d = c & 63;
#pragma unroll
        for (int j = 0; j < 8; ++j) {
            int rl = j * 16 + rbase;
            uint4 val = *(const uint4*)(smem + rl * 128 + (c ^ ((rl & 15) << 3)));
            *(uint4*)(dst0 + (size_t)((b * NH + h) * SEQ + n0 + rl) * HD + d) = val;
        }
    } else {
        // V: transpose through LDS, write V^T coalesced
        const int vblk = colBlk - 2 * CH;
        __syncthreads();
#pragma unroll
        for (int mi = 0; mi < 4; ++mi)
#pragma unroll
            for (int ni = 0; ni < 4; ++ni)
#pragma unroll
                for (int r = 0; r < 4; ++r) {
                    int rl = wm * 64 + mi * 16 + quad * 4 + r;   // n-local
                    int cl = wn * 64 + ni * 16 + l16;            // d-local
                    smem[cl * 128 + (((rl >> 3) ^ (cl & 15)) << 3) + (rl & 7)] =
                        (__bf16)acc[mi][ni][r];
                }
        __syncthreads();
        const int dl = tid >> 1;
        const int d  = vblk + dl;
        const int h  = d >> 6, dd = d & 63;
        const size_t base = (size_t)((b * NH + h) * HD + dd) * SEQ + n0;
#pragma unroll
        for (int j2 = 0; j2 < 8; ++j2) {
            int j = (tid & 1) * 8 + j2;
            uint4 val = *(const uint4*)(smem + dl * 128 + ((j ^ (dl & 15)) << 3));
            *(uint4*)(Vt + base + j * 8) = val;
        }
    }
}

// ---------------- Flash attention v9 (RESTORED R0 — proven 67us): 128-key staging tiles ------
// Block = 4 waves, 128 queries. Per iteration: stage 128 keys of K + V^T (32 KB, 8 DMAs)
// behind one barrier pair, then run the proven 64-key body on each sub-tile.
// R1-R6 established: ring-pipeline/counted-vmcnt (R1), V-from-global (R2), 64q-wave-split
// (R3-R6) all lose to this structure — it is dependency-latency bound at ~770 TF.
__global__ __launch_bounds__(256, 3) void flash_attn(const __bf16* __restrict__ Qb,
                                                     const __bf16* __restrict__ Kb,
                                                     const __bf16* __restrict__ Vt,
                                                     __bf16* __restrict__ Ab) {
    __shared__ __bf16 smem[16384];       // 32 KB: Ks0|Vs0|Ks1|Vs1 (4KB elements each)
                                         // epilogue reuses first 18 KB as [128][72]

    const int tid  = threadIdx.x;
    const int lane = tid & 63, wid = tid >> 6;
    const int quad = lane >> 4, l16 = lane & 15;

    // XCD-aware decode: blk%8 = XCD; 6 bh x 16 qblk per XCD.
    const int lin  = blockIdx.x;              // 0..767
    const int xcd  = lin & 7, idx = lin >> 3; // idx 0..95
    const int bh   = xcd * 6 + (idx >> 4);    // 0..47
    const int qblk = idx & 15;                // 0..15 (128 queries each)
    const int b    = bh / NH, head = bh - b * NH;

    const int qA = qblk * 128 + wid * 16 + l16;
    const int qB = qA + 64;

    // Q^T B-frags (held whole kernel): lane n=l16=q, k(d) = kcd*32 + quad*8 + j
    bf16x8 qfA[2], qfB[2];
#pragma unroll
    for (int kcd = 0; kcd < 2; ++kcd) {
        qfA[kcd] = *(const bf16x8*)(Qb + (size_t)(bh * SEQ + qA) * HD + kcd * 32 + quad * 8);
        qfB[kcd] = *(const bf16x8*)(Qb + (size_t)(bh * SEQ + qB) * HD + kcd * 32 + quad * 8);
    }

    // key permutation (even/odd groups) for zero-cndmask P exchange
    const int key_e = ((l16 >> 2) << 3) + (l16 & 3);
    const int key_o = ((((l16 >> 2) ^ 1)) << 3) + 4 + (l16 & 3);

    f32x4 otA[4], otB[4];
    f32x4 z = {0.f, 0.f, 0.f, 0.f};
#pragma unroll
    for (int dg = 0; dg < 4; ++dg) { otA[dg] = z; otB[dg] = z; }
    float lA = 0.f, lB = 0.f;

    const __bf16* Kbh = Kb + (size_t)bh * SEQ * HD;
    const __bf16* Vbh = Vt + (size_t)bh * HD * SEQ;

    const int s_row = tid >> 3, s_pc = tid & 7;
    const int s_lc0 = s_pc ^ SWZ(s_row);
    const int s_lc1 = s_pc ^ SWZ(s_row + 32);

// proven R8 64-key body on sub-tile at (Ks, Vs)
#define PROCESS(Ks, Vs)                                                                       \
    do {                                                                                      \
        f32x4 stA[4], stB[4];                                                                 \
        _Pragma("unroll")                                                                     \
        for (int g = 0; g < 4; ++g) { stA[g] = z; stB[g] = z; }                               \
        _Pragma("unroll")                                                                     \
        for (int g = 0; g < 4; ++g) {                                                         \
            const int key = ((g >> 1) << 5) + ((g & 1) ? key_o : key_e);                      \
            _Pragma("unroll")                                                                 \
            for (int kcd = 0; kcd < 2; ++kcd) {                                               \
                int c8 = quad + (kcd << 2);                                                   \
                bf16x8 kf = *(const bf16x8*)((Ks) + key * 64 + ((c8 ^ SWZ(key)) << 3));       \
                stA[g] = MFMA16(kf, qfA[kcd], stA[g]);                                        \
                stB[g] = MFMA16(kf, qfB[kcd], stB[g]);                                        \
            }                                                                                 \
        }                                                                                     \
        bf16x8 pfA[2], pfB[2];                                                                \
        _Pragma("unroll")                                                                     \
        for (int g = 0; g < 4; ++g)                                                           \
            _Pragma("unroll")                                                                 \
            for (int r = 0; r < 4; ++r) {                                                     \
                float p = EXP2(stA[g][r]);                                                    \
                stA[g][r] = p;                                                                \
                lA += p;                                                                      \
            }                                                                                 \
        _Pragma("unroll")                                                                     \
        for (int kk = 0; kk < 2; ++kk) {                                                      \
            unsigned w0 = pack2(stA[2 * kk][0], stA[2 * kk][1]);                              \
            unsigned w1 = pack2(stA[2 * kk][2], stA[2 * kk][3]);                              \
            unsigned x0 = pack2(stA[2 * kk + 1][0], stA[2 * kk + 1][1]);                      \
            unsigned x1 = pack2(stA[2 * kk + 1][2], stA[2 * kk + 1][3]);                      \
            unsigned w2 = (unsigned)__shfl_xor((int)x0, 16, 64);                              \
            unsigned w3 = (unsigned)__shfl_xor((int)x1, 16, 64);                              \
            union { bf16x8 v; unsigned u[4]; } f;                                             \
            f.u[0] = w0; f.u[1] = w1; f.u[2] = w2; f.u[3] = w3;                               \
            pfA[kk] = f.v;                                                                    \
        }                                                                                     \
        _Pragma("unroll")                                                                     \
        for (int g = 0; g < 4; ++g)                                                           \
            _Pragma("unroll")                                                                 \
            for (int r = 0; r < 4; ++r) {                                                     \
                float p = EXP2(stB[g][r]);                                                    \
                stB[g][r] = p;                                                                \
                lB += p;                                                                      \
            }                                                                                 \
        _Pragma("unroll")                                                                     \
        for (int kk = 0; kk < 2; ++kk) {                                                      \
            unsigned w0 = pack2(stB[2 * kk][0], stB[2 * kk][1]);                              \
            unsigned w1 = pack2(stB[2 * kk][2], stB[2 * kk][3]);                              \
            unsigned x0 = pack2(stB[2 * kk + 1][0], stB[2 * kk + 1][1]);                      \
            unsigned x1 = pack2(stB[2 * kk + 1][2], stB[2 * kk + 1][3]);                      \
            unsigned w2 = (unsigned)__shfl_xor((int)x0, 16, 64);                              \
            unsigned w3 = (unsigned)__shfl_xor((int)x1, 16, 64);                              \
            union { bf16x8 v; unsigned u[4]; } f;                                             \
            f.u[0] = w0; f.u[1] = w1; f.u[2] = w2; f.u[3] = w3;                               \
            pfB[kk] = f.v;                                                                    \
        }                                                                                    \
        _Pragma("unroll")                                                                     \
        for (int dg = 0; dg < 4; ++dg)                                                        \
            _Pragma("unroll")                                                                 \
            for (int kk = 0; kk < 2; ++kk) {                                                  \
                int row = (dg << 4) + l16;                                                    \
                int c8 = quad + (kk << 2);                                                    \
                bf16x8 vf = *(const bf16x8*)((Vs) + row * 64 + ((c8 ^ SWZ(row)) << 3));       \
                otA[dg] = MFMA16(vf, pfA[kk], otA[dg]);                                       \
                otB[dg] = MFMA16(vf, pfB[kk], otB[dg]);                                       \
            }                                                                                 \
    } while (0)

    for (int kb = 0; kb < SEQ / 128; ++kb) {
        const int kbase = kb * 128;
        __syncthreads();   // prior-iteration LDS readers done
        // sub-tile 0: keys kbase..kbase+63
        lds_dma16(Kbh + (size_t)(kbase + s_row) * HD + s_lc0 * 8,            smem + tid * 8);
        lds_dma16(Kbh + (size_t)(kbase + s_row + 32) * HD + s_lc1 * 8,       smem + 2048 + tid * 8);
        lds_dma16(Vbh + (size_t)s_row * SEQ + kbase + s_lc0 * 8,             smem + 4096 + tid * 8);
        lds_dma16(Vbh + (size_t)(s_row + 32) * SEQ + kbase + s_lc1 * 8,      smem + 6144 + tid * 8);
        // sub-tile 1: keys kbase+64..kbase+127
        lds_dma16(Kbh + (size_t)(kbase + 64 + s_row) * HD + s_lc0 * 8,       smem + 8192 + tid * 8);
        lds_dma16(Kbh + (size_t)(kbase + 96 + s_row) * HD + s_lc1 * 8,       smem + 10240 + tid * 8);
        lds_dma16(Vbh + (size_t)s_row * SEQ + kbase + 64 + s_lc0 * 8,        smem + 12288 + tid * 8);
        lds_dma16(Vbh + (size_t)(s_row + 32) * SEQ + kbase + 64 + s_lc1 * 8, smem + 14336 + tid * 8);
        __syncthreads();   // drains dma

        PROCESS(smem, smem + 4096);
        PROCESS(smem + 8192, smem + 12288);
    }
#undef PROCESS

    lA += __shfl_xor(lA, 16, 64);
    lA += __shfl_xor(lA, 32, 64);
    lB += __shfl_xor(lB, 16, 64);
    lB += __shfl_xor(lB, 32, 64);
    const float rA = 1.f / lA, rB = 1.f / lB;

    __syncthreads();   // reuse smem as [128][72] for O transpose
    __bf16 (*Ob)[72] = (__bf16(*)[72])smem;
#pragma unroll
    for (int dg = 0; dg < 4; ++dg)
#pragma unroll
        for (int r = 0; r < 4; ++r) {
            int d = (dg << 4) + (quad << 2) + r;
            Ob[wid * 16 + l16][d]      = (__bf16)(otA[dg][r] * rA);
            Ob[64 + wid * 16 + l16][d] = (__bf16)(otB[dg][r] * rB);
        }
    __syncthreads();
    {
        const int row = tid >> 1, c0 = (tid & 1) * 32;
        __bf16* dst = Ab + (size_t)(b * SEQ + qblk * 128 + row) * CH + head * HD + c0;
#pragma unroll
        for (int j = 0; j < 4; ++j)
            *(uint4*)(dst + j * 8) = *(const uint4*)(&Ob[row][c0 + j * 8]);
    }
}

// ---------------- Projection GEMM: Attn(8192x768) @ proj_w(768x768)^T + bias ----------------
__global__ __launch_bounds__(256) void proj_gemm(const __bf16* __restrict__ Ab,
                                                 const __bf16* __restrict__ Pw,
                                                 const float* __restrict__ bias,
                                                 float* __restrict__ out) {
    __shared__ __bf16 As[128 * 64];
    __shared__ __bf16 Bs[128 * 64];
    f32x4 acc[4][4];
    const int rowBlk = blockIdx.x * 128, colBlk = blockIdx.y * 128;
    gemm128_loop(Ab, Pw, CH, rowBlk, colBlk, As, Bs, acc);

    const int lane = threadIdx.x & 63, wid = threadIdx.x >> 6;
    const int quad = lane >> 4, l16 = lane & 15, wm = wid >> 1, wn = wid & 1;
#pragma unroll
    for (int mi = 0; mi < 4; ++mi)
#pragma unroll
        for (int ni = 0; ni < 4; ++ni)
#pragma unroll
            for (int r = 0; r < 4; ++r) {
                int row = rowBlk + wm * 64 + mi * 16 + quad * 4 + r;
                int col = colBlk + wn * 64 + ni * 16 + l16;
                out[(size_t)row * CH + col] = acc[mi][ni][r] + bias[col];
            }
}

extern "C" void kernel_launch(void* const* d_in, const int* in_sizes, int n_in,
                              void* d_out, int out_size, void* d_ws, size_t ws_size,
                              hipStream_t stream) {
    const float* x      = (const float*)d_in[0];
    const float* qkv_w  = (const float*)d_in[1];
    const float* proj_w = (const float*)d_in[2];
    const float* proj_b = (const float*)d_in[3];
    float* out = (float*)d_out;

    char* ws = (char*)d_ws;
    const size_t nX = (size_t)B_SZ * SEQ * CH;
    const size_t nW = (size_t)3 * CH * CH;
    const size_t nP = (size_t)CH * CH;
    const size_t nQ = (size_t)B_SZ * NH * SEQ * HD;

    __bf16* Xb = (__bf16*)(ws);
    __bf16* Wb = (__bf16*)(ws + 2 * nX);
    __bf16* Pw = (__bf16*)(ws + 2 * (nX + nW));
    __bf16* Qb = (__bf16*)(ws + 2 * (nX + nW + nP));
    __bf16* Kb = (__bf16*)(ws + 2 * (nX + nW + nP + nQ));
    __bf16* Vt = (__bf16*)(ws + 2 * (nX + nW + nP + 2 * nQ));
    __bf16* Ab = (__bf16*)(ws + 2 * (nX + nW + nP + 3 * nQ));

    convert_all<<<NBLK_X + NBLK_W + NBLK_P, 256, 0, stream>>>(x, qkv_w, proj_w, Xb, Wb, Pw);

    qkv_gemm<<<dim3((B_SZ * SEQ) / 128, (3 * CH) / 128), 256, 0, stream>>>(Xb, Wb, Qb, Kb, Vt);

    flash_attn<<<768, 256, 0, stream>>>(Qb, Kb, Vt, Ab);

    proj_gemm<<<dim3((B_SZ * SEQ) / 128, CH / 128), 256, 0, stream>>>(Ab, Pw, proj_b, out);
}